// Round 1
// baseline (1118.010 us; speedup 1.0000x reference)
//
#include <hip/hip_runtime.h>
#include <math.h>

#define NN 10000
#define NE 131072

__device__ __forceinline__ float silu_f(float x) {
    return x / (1.0f + __expf(-x));
}

// ---------------------------------------------------------------------------
// Kernel 1: per-node MLP  embed(16) -> 64 -> 32 -> 8  (Ai)
// ---------------------------------------------------------------------------
__global__ __launch_bounds__(256)
void node_mlp_kernel(const int* __restrict__ A,
                     const float* __restrict__ emb_tab,
                     const float* __restrict__ W1, const float* __restrict__ b1,
                     const float* __restrict__ W2, const float* __restrict__ b2,
                     const float* __restrict__ W3, const float* __restrict__ b3,
                     float* __restrict__ Ai)
{
    int n = blockIdx.x * blockDim.x + threadIdx.x;
    if (n >= NN) return;
    int a = A[n];
    float h[16];
#pragma unroll
    for (int i = 0; i < 16; ++i) h[i] = emb_tab[a * 16 + i];

    float h1[64];
#pragma unroll
    for (int j = 0; j < 64; ++j) h1[j] = b1[j];
#pragma unroll
    for (int i = 0; i < 16; ++i) {
        float hv = h[i];
#pragma unroll
        for (int j = 0; j < 64; ++j) h1[j] += hv * W1[i * 64 + j];
    }
#pragma unroll
    for (int j = 0; j < 64; ++j) h1[j] = silu_f(h1[j]);

    float h2[32];
#pragma unroll
    for (int j = 0; j < 32; ++j) h2[j] = b2[j];
#pragma unroll
    for (int i = 0; i < 64; ++i) {
        float hv = h1[i];
#pragma unroll
        for (int j = 0; j < 32; ++j) h2[j] += hv * W2[i * 32 + j];
    }
#pragma unroll
    for (int j = 0; j < 32; ++j) h2[j] = silu_f(h2[j]);

#pragma unroll
    for (int j = 0; j < 8; ++j) {
        float s = b3[j];
#pragma unroll
        for (int i = 0; i < 32; ++i) s += h2[i] * W3[i * 8 + j];
        Ai[n * 8 + j] = s;
    }
}

// ---------------------------------------------------------------------------
// Kernel 2: per-edge — geometry, radial MLP, bilinear contraction w/ fc_W4,
// spherical harmonics, atomic segment-sum into out + counts.
// ---------------------------------------------------------------------------
__global__ __launch_bounds__(256, 2)
void edge_kernel(const float* __restrict__ pos,
                 const int* __restrict__ batch,
                 const int* __restrict__ esrc,
                 const int* __restrict__ edst,
                 const float* __restrict__ shifts,
                 const float* __restrict__ cell,
                 const float* __restrict__ fcW1,
                 const float* __restrict__ fcW2,
                 const float* __restrict__ fcW3,
                 const float* __restrict__ fcW4,
                 const float* __restrict__ Ai,
                 float* __restrict__ accum,
                 float* __restrict__ counts)
{
    // w3 kept in LDS transposed [k][tid]: dynamic index k in the rolled K-loop
    // without spilling a register array to scratch. lanes hit consecutive
    // banks -> conflict-free. Same-thread write/read: no barrier needed.
    __shared__ float w3s[64][256];

    int e = blockIdx.x * 256 + threadIdx.x;
    if (e >= NE) return;
    int s = esrc[e], d = edst[e];
    int b = batch[s];
    const float* C = cell + b * 9;
    float sx = shifts[e * 3 + 0], sy = shifts[e * 3 + 1], sz = shifts[e * 3 + 2];
    float vx = pos[d * 3 + 0] - pos[s * 3 + 0] + sx * C[0] + sy * C[3] + sz * C[6];
    float vy = pos[d * 3 + 1] - pos[s * 3 + 1] + sx * C[1] + sy * C[4] + sz * C[7];
    float vz = pos[d * 3 + 2] - pos[s * 3 + 2] + sx * C[2] + sy * C[5] + sz * C[8];
    float len = sqrtf(vx * vx + vy * vy + vz * vz);
    float inv = 1.0f / fmaxf(len, 1e-9f);
    float ux = vx * inv, uy = vy * inv, uz = vz * inv;

    // soft_one_hot * sqrt(10) then @fc_W1/sqrt(10): the sqrt(10) cancels.
    // values_i = 4(i+1)/11, step = 4/11  =>  diff = len*2.75 - (i+1)
    float embv[10];
    float base = len * 2.75f;
#pragma unroll
    for (int i = 0; i < 10; ++i) {
        float dd = base - (float)(i + 1);
        embv[i] = __expf(-dd * dd) * (1.0f / 1.12f);
    }

    // w1 = silu(emb @ fcW1)
    float w1v[64];
#pragma unroll
    for (int j = 0; j < 64; ++j) w1v[j] = 0.f;
#pragma unroll
    for (int i = 0; i < 10; ++i) {
        float hv = embv[i];
#pragma unroll
        for (int j = 0; j < 64; ++j) w1v[j] += hv * fcW1[i * 64 + j];
    }
#pragma unroll
    for (int j = 0; j < 64; ++j) w1v[j] = silu_f(w1v[j]);

    // w2 = silu(w1 @ fcW2 / 8)
    float w2v[64];
#pragma unroll
    for (int j = 0; j < 64; ++j) w2v[j] = 0.f;
#pragma unroll
    for (int i = 0; i < 64; ++i) {
        float hv = w1v[i];
#pragma unroll
        for (int j = 0; j < 64; ++j) w2v[j] += hv * fcW2[i * 64 + j];
    }
#pragma unroll
    for (int j = 0; j < 64; ++j) w2v[j] = silu_f(w2v[j] * 0.125f);

    // w3 = silu(w2 @ fcW3 / 8) -> LDS (reuse w1v as accumulator)
#pragma unroll
    for (int j = 0; j < 64; ++j) w1v[j] = 0.f;
#pragma unroll
    for (int i = 0; i < 64; ++i) {
        float hv = w2v[i];
#pragma unroll
        for (int j = 0; j < 64; ++j) w1v[j] += hv * fcW3[i * 64 + j];
    }
#pragma unroll
    for (int j = 0; j < 64; ++j) w3s[j][threadIdx.x] = silu_f(w1v[j] * 0.125f);

    float As[8], Ad[8];
#pragma unroll
    for (int i = 0; i < 8; ++i) As[i] = Ai[s * 8 + i];
#pragma unroll
    for (int i = 0; i < 8; ++i) Ad[i] = Ai[d * 8 + i];

    // t[c] = sum_k w3[k] * sum_{u,v} As[u]*Ad[v]*W4[k, n(l,uv,w)]
    // fc_W4 row layout: [l0: uv*16+w (w<16)][l1: 1024+uv*8+w][l2: 1536+uv*4+w]
    float acc[28];
#pragma unroll
    for (int c = 0; c < 28; ++c) acc[c] = 0.f;

#pragma unroll 1
    for (int k = 0; k < 64; ++k) {
        float wk = w3s[k][threadIdx.x];
        const float4* __restrict__ row = (const float4*)(fcW4 + k * 1792);
#pragma unroll
        for (int u = 0; u < 8; ++u) {
            float wku = wk * As[u];
#pragma unroll
            for (int v = 0; v < 8; ++v) {
                float g = wku * Ad[v];
                int uv = u * 8 + v;
                float4 q0 = row[uv * 4 + 0];
                float4 q1 = row[uv * 4 + 1];
                float4 q2 = row[uv * 4 + 2];
                float4 q3 = row[uv * 4 + 3];
                float4 r0 = row[256 + uv * 2 + 0];
                float4 r1 = row[256 + uv * 2 + 1];
                float4 p0 = row[384 + uv];
                acc[0]  += g * q0.x; acc[1]  += g * q0.y; acc[2]  += g * q0.z; acc[3]  += g * q0.w;
                acc[4]  += g * q1.x; acc[5]  += g * q1.y; acc[6]  += g * q1.z; acc[7]  += g * q1.w;
                acc[8]  += g * q2.x; acc[9]  += g * q2.y; acc[10] += g * q2.z; acc[11] += g * q2.w;
                acc[12] += g * q3.x; acc[13] += g * q3.y; acc[14] += g * q3.z; acc[15] += g * q3.w;
                acc[16] += g * r0.x; acc[17] += g * r0.y; acc[18] += g * r0.z; acc[19] += g * r0.w;
                acc[20] += g * r1.x; acc[21] += g * r1.y; acc[22] += g * r1.z; acc[23] += g * r1.w;
                acc[24] += g * p0.x; acc[25] += g * p0.y; acc[26] += g * p0.z; acc[27] += g * p0.w;
            }
        }
    }

    // spherical harmonics (unit vector) and scatter with 1/64 scale
    const float s3c  = 1.7320508075688772f;
    const float s5c  = 2.2360679774997896f;
    const float s15c = 3.872983346207417f;
    float sh1v[3];
    sh1v[0] = s3c * ux; sh1v[1] = s3c * uy; sh1v[2] = s3c * uz;
    float sh2v[5];
    sh2v[0] = s15c * ux * uz;
    sh2v[1] = s15c * ux * uy;
    sh2v[2] = s5c * (uy * uy - 0.5f * (ux * ux + uz * uz));
    sh2v[3] = s15c * uy * uz;
    sh2v[4] = 0.5f * s15c * (uz * uz - ux * ux);

    float* orow = accum + d * 60;
    const float sc = 1.0f / 64.0f;
#pragma unroll
    for (int w = 0; w < 16; ++w)
        atomicAdd(orow + w, acc[w] * sc);
#pragma unroll
    for (int w = 0; w < 8; ++w) {
        float tw = acc[16 + w] * sc;
#pragma unroll
        for (int m = 0; m < 3; ++m)
            atomicAdd(orow + 16 + w * 3 + m, tw * sh1v[m]);
    }
#pragma unroll
    for (int w = 0; w < 4; ++w) {
        float tw = acc[24 + w] * sc;
#pragma unroll
        for (int m = 0; m < 5; ++m)
            atomicAdd(orow + 40 + w * 5 + m, tw * sh2v[m]);
    }
    atomicAdd(counts + d, 1.0f);
}

// ---------------------------------------------------------------------------
// Kernel 3: divide by max(counts, 1)
// ---------------------------------------------------------------------------
__global__ __launch_bounds__(256)
void finalize_kernel(float* __restrict__ out, const float* __restrict__ counts)
{
    int i = blockIdx.x * 256 + threadIdx.x;
    if (i >= NN * 60) return;
    int n = i / 60;
    out[i] = out[i] / fmaxf(counts[n], 1.0f);
}

extern "C" void kernel_launch(void* const* d_in, const int* in_sizes, int n_in,
                              void* d_out, int out_size, void* d_ws, size_t ws_size,
                              hipStream_t stream)
{
    const float* pos     = (const float*)d_in[0];
    const int*   A       = (const int*)d_in[1];
    const int*   batch   = (const int*)d_in[2];
    const int*   esrc    = (const int*)d_in[3];
    const int*   edst    = (const int*)d_in[4];
    const float* shifts  = (const float*)d_in[5];
    const float* cell    = (const float*)d_in[6];
    const float* emb_tab = (const float*)d_in[7];
    const float* fitW1   = (const float*)d_in[8];
    const float* fitb1   = (const float*)d_in[9];
    const float* fitW2   = (const float*)d_in[10];
    const float* fitb2   = (const float*)d_in[11];
    const float* fitW3   = (const float*)d_in[12];
    const float* fitb3   = (const float*)d_in[13];
    const float* fcW1    = (const float*)d_in[14];
    const float* fcW2    = (const float*)d_in[15];
    const float* fcW3    = (const float*)d_in[16];
    const float* fcW4    = (const float*)d_in[17];

    float* out    = (float*)d_out;          // used as the atomic accumulator
    float* Ai     = (float*)d_ws;           // NN*8 floats
    float* counts = Ai + NN * 8;            // NN floats

    hipMemsetAsync(d_out, 0, (size_t)NN * 60 * sizeof(float), stream);
    hipMemsetAsync(counts, 0, (size_t)NN * sizeof(float), stream);

    node_mlp_kernel<<<(NN + 255) / 256, 256, 0, stream>>>(
        A, emb_tab, fitW1, fitb1, fitW2, fitb2, fitW3, fitb3, Ai);

    edge_kernel<<<NE / 256, 256, 0, stream>>>(
        pos, batch, esrc, edst, shifts, cell,
        fcW1, fcW2, fcW3, fcW4, Ai, out, counts);

    finalize_kernel<<<(NN * 60 + 255) / 256, 256, 0, stream>>>(out, counts);
}

// Round 2
// 921.388 us; speedup vs baseline: 1.2134x; 1.2134x over previous
//
#include <hip/hip_runtime.h>
#include <hip/hip_bf16.h>
#include <math.h>

#define NN 10000
#define NE 131072

typedef __attribute__((ext_vector_type(8))) short short8;
typedef __attribute__((ext_vector_type(4))) float f32x4;

__device__ __forceinline__ float silu_f(float x) {
    return x / (1.0f + __expf(-x));
}

// round-to-nearest-even f32 -> bf16 (finite inputs only)
__device__ __forceinline__ unsigned short f2bf(float f) {
    unsigned int u = __float_as_uint(f);
    u += 0x7FFFu + ((u >> 16) & 1u);
    return (unsigned short)(u >> 16);
}

// packed pair via HW v_cvt_pk_bf16_f32 (x = low half)
__device__ __forceinline__ unsigned int pk_bf16(float lo, float hi) {
    __hip_bfloat162 h = __float22bfloat162_rn(float2{lo, hi});
    return *reinterpret_cast<unsigned int*>(&h);
}

// ---------------------------------------------------------------------------
// Kernel 1: per-node MLP  embed(16) -> 64 -> 32 -> 8  (Ai)
// ---------------------------------------------------------------------------
__global__ __launch_bounds__(256)
void node_mlp_kernel(const int* __restrict__ A,
                     const float* __restrict__ emb_tab,
                     const float* __restrict__ W1, const float* __restrict__ b1,
                     const float* __restrict__ W2, const float* __restrict__ b2,
                     const float* __restrict__ W3, const float* __restrict__ b3,
                     float* __restrict__ Ai)
{
    int n = blockIdx.x * blockDim.x + threadIdx.x;
    if (n >= NN) return;
    int a = A[n];
    float h[16];
#pragma unroll
    for (int i = 0; i < 16; ++i) h[i] = emb_tab[a * 16 + i];

    float h1[64];
#pragma unroll
    for (int j = 0; j < 64; ++j) h1[j] = b1[j];
#pragma unroll
    for (int i = 0; i < 16; ++i) {
        float hv = h[i];
#pragma unroll
        for (int j = 0; j < 64; ++j) h1[j] += hv * W1[i * 64 + j];
    }
#pragma unroll
    for (int j = 0; j < 64; ++j) h1[j] = silu_f(h1[j]);

    float h2[32];
#pragma unroll
    for (int j = 0; j < 32; ++j) h2[j] = b2[j];
#pragma unroll
    for (int i = 0; i < 64; ++i) {
        float hv = h1[i];
#pragma unroll
        for (int j = 0; j < 32; ++j) h2[j] += hv * W2[i * 32 + j];
    }
#pragma unroll
    for (int j = 0; j < 32; ++j) h2[j] = silu_f(h2[j]);

#pragma unroll
    for (int j = 0; j < 8; ++j) {
        float s = b3[j];
#pragma unroll
        for (int i = 0; i < 32; ++i) s += h2[i] * W3[i * 8 + j];
        Ai[n * 8 + j] = s;
    }
}

// ---------------------------------------------------------------------------
// Kernel 2: per-edge geometry + radial MLP -> w3 (bf16, transposed [64][NE])
//           + unit vectors [NE*3]
// ---------------------------------------------------------------------------
__global__ __launch_bounds__(256, 2)
void edge_mlp_kernel(const float* __restrict__ pos,
                     const int* __restrict__ batch,
                     const int* __restrict__ esrc,
                     const int* __restrict__ edst,
                     const float* __restrict__ shifts,
                     const float* __restrict__ cell,
                     const float* __restrict__ fcW1,
                     const float* __restrict__ fcW2,
                     const float* __restrict__ fcW3,
                     unsigned short* __restrict__ w3gT,
                     float* __restrict__ unit)
{
    int e = blockIdx.x * 256 + threadIdx.x;
    if (e >= NE) return;
    int s = esrc[e], d = edst[e];
    int b = batch[s];
    const float* C = cell + b * 9;
    float sx = shifts[e * 3 + 0], sy = shifts[e * 3 + 1], sz = shifts[e * 3 + 2];
    float vx = pos[d * 3 + 0] - pos[s * 3 + 0] + sx * C[0] + sy * C[3] + sz * C[6];
    float vy = pos[d * 3 + 1] - pos[s * 3 + 1] + sx * C[1] + sy * C[4] + sz * C[7];
    float vz = pos[d * 3 + 2] - pos[s * 3 + 2] + sx * C[2] + sy * C[5] + sz * C[8];
    float len = sqrtf(vx * vx + vy * vy + vz * vz);
    float inv = 1.0f / fmaxf(len, 1e-9f);
    unit[e * 3 + 0] = vx * inv;
    unit[e * 3 + 1] = vy * inv;
    unit[e * 3 + 2] = vz * inv;

    // soft_one_hot: the sqrt(10) of emb and /sqrt(10) of fc_W1 cancel.
    float embv[10];
    float base = len * 2.75f;
#pragma unroll
    for (int i = 0; i < 10; ++i) {
        float dd = base - (float)(i + 1);
        embv[i] = __expf(-dd * dd) * (1.0f / 1.12f);
    }

    float w1v[64];
#pragma unroll
    for (int j = 0; j < 64; ++j) w1v[j] = 0.f;
#pragma unroll
    for (int i = 0; i < 10; ++i) {
        float hv = embv[i];
#pragma unroll
        for (int j = 0; j < 64; ++j) w1v[j] += hv * fcW1[i * 64 + j];
    }
#pragma unroll
    for (int j = 0; j < 64; ++j) w1v[j] = silu_f(w1v[j]);

    float w2v[64];
#pragma unroll
    for (int j = 0; j < 64; ++j) w2v[j] = 0.f;
#pragma unroll
    for (int i = 0; i < 64; ++i) {
        float hv = w1v[i];
#pragma unroll
        for (int j = 0; j < 64; ++j) w2v[j] += hv * fcW2[i * 64 + j];
    }
#pragma unroll
    for (int j = 0; j < 64; ++j) w2v[j] = silu_f(w2v[j] * 0.125f);

#pragma unroll
    for (int j = 0; j < 64; ++j) w1v[j] = 0.f;
#pragma unroll
    for (int i = 0; i < 64; ++i) {
        float hv = w2v[i];
#pragma unroll
        for (int j = 0; j < 64; ++j) w1v[j] += hv * fcW3[i * 64 + j];
    }
    // w3 = silu(./8), stored transposed for coalesced store AND coalesced
    // staging in the gemm kernel.
#pragma unroll
    for (int k = 0; k < 64; ++k)
        w3gT[k * NE + e] = f2bf(silu_f(w1v[k] * 0.125f));
}

// ---------------------------------------------------------------------------
// Kernel 3: build B = fc_W4 re-laid out as bf16 [K=4096][N=32] pre-swizzled
// into MFMA-fragment order:
//   flat = ((((chunk*8 + sub)*2 + nt)*4 + q)*16 + nn)*8 + j
//   kuv = chunk*256 + sub*32 + q*8 + j ;  wc = nt*16 + nn
//   (k = kuv/64, uv = kuv%64;  wc: [0,16)=l0 w, [16,24)=l1 w, [24,28)=l2 w)
// ---------------------------------------------------------------------------
__global__ __launch_bounds__(256)
void prep_B_kernel(const float* __restrict__ fcW4, unsigned short* __restrict__ Bg)
{
    int i = blockIdx.x * 256 + threadIdx.x;   // [0, 131072)
    int j  = i & 7;
    int nn = (i >> 3) & 15;
    int q  = (i >> 7) & 3;
    int nt = (i >> 9) & 1;
    int sub = (i >> 10) & 7;
    int chunk = i >> 13;
    int kuv = (chunk << 8) + (sub << 5) + (q << 3) + j;
    int k = kuv >> 6;
    int uv = kuv & 63;
    int wc = (nt << 4) + nn;
    float v;
    if (wc < 16)      v = fcW4[k * 1792 + uv * 16 + wc];
    else if (wc < 24) v = fcW4[k * 1792 + 1024 + uv * 8 + (wc - 16)];
    else if (wc < 28) v = fcW4[k * 1792 + 1536 + uv * 4 + (wc - 24)];
    else              v = 0.0f;
    Bg[i] = f2bf(v);
}

// ---------------------------------------------------------------------------
// Kernel 4: MFMA GEMM  C[e, wc] = sum_kuv G[e,kuv] * B[kuv,wc]
//   G[e, k*64+u*8+v] = w3[e,k] * As[e,u] * Ad[e,v]   (built in-register)
// 128 edges/block (4 waves x 2 M-tiles of 16), K in 16 chunks of 256,
// B chunk (16KB) double-buffered in LDS via global_load_lds width=16.
// Epilogue: sh factors + atomic scatter (unchanged semantics).
// ---------------------------------------------------------------------------
__global__ __launch_bounds__(256, 2)
void gemm_kernel(const int* __restrict__ esrc,
                 const int* __restrict__ edst,
                 const float* __restrict__ Ai,
                 const unsigned short* __restrict__ w3gT,
                 const float* __restrict__ unit,
                 const uint4* __restrict__ Bg,
                 float* __restrict__ outAcc,
                 float* __restrict__ counts)
{
    __shared__ uint4 Bs[2048];                 // 2 x 16KB
    __shared__ unsigned short w3s[128 * 66];   // [block-edge][k], +2 pad

    const int tid  = threadIdx.x;
    const int wave = tid >> 6;
    const int lane = tid & 63;
    const int q    = lane >> 4;
    const int n    = lane & 15;
    const int be0  = blockIdx.x * 128;
    const int we0  = be0 + wave * 32;

    // stage w3 for the block's 128 edges: coalesced global, scattered LDS
    {
        const unsigned int* g = (const unsigned int*)w3gT;  // [64][NE/2] uints
        const int colbase = be0 >> 1;
#pragma unroll
        for (int it = 0; it < 16; ++it) {
            int idx = it * 256 + tid;          // 0..4095
            int k  = idx >> 6;
            int cc = idx & 63;
            unsigned int v = g[k * (NE / 2) + colbase + cc];
            w3s[(2 * cc)     * 66 + k] = (unsigned short)(v & 0xFFFFu);
            w3s[(2 * cc + 1) * 66 + k] = (unsigned short)(v >> 16);
        }
    }

    // per-lane loop-invariant edge factors (A-operand rows: m = lane&15)
    float Asq[2], Asq4[2], Ad[2][8];
#pragma unroll
    for (int t = 0; t < 2; ++t) {
        int eA = we0 + t * 16 + n;
        int s = esrc[eA], d = edst[eA];
        Asq[t]  = Ai[s * 8 + q];
        Asq4[t] = Ai[s * 8 + 4 + q];
        float4 d0 = *(const float4*)&Ai[d * 8];
        float4 d1 = *(const float4*)&Ai[d * 8 + 4];
        Ad[t][0] = d0.x; Ad[t][1] = d0.y; Ad[t][2] = d0.z; Ad[t][3] = d0.w;
        Ad[t][4] = d1.x; Ad[t][5] = d1.y; Ad[t][6] = d1.z; Ad[t][7] = d1.w;
    }

    f32x4 acc[2][2];
#pragma unroll
    for (int t = 0; t < 2; ++t)
#pragma unroll
        for (int nt = 0; nt < 2; ++nt)
            acc[t][nt] = (f32x4){0.f, 0.f, 0.f, 0.f};

    auto stage = [&](int chunk, int buf) {
#pragma unroll
        for (int it = 0; it < 4; ++it) {
            int sect = it * 4 + wave;                       // 0..15
            const uint4* gp = Bg + chunk * 1024 + sect * 64 + lane;
            uint4* lp = &Bs[buf * 1024 + sect * 64];        // wave-uniform base
            __builtin_amdgcn_global_load_lds(
                (const __attribute__((address_space(1))) unsigned int*)gp,
                (__attribute__((address_space(3))) unsigned int*)lp,
                16, 0, 0);
        }
    };

    union AFrag { unsigned int u[4]; short8 s8; };

    stage(0, 0);
    __syncthreads();

#pragma unroll 1
    for (int c = 0; c < 16; ++c) {
        int buf = c & 1;
        if (c < 15) stage(c + 1, buf ^ 1);
#pragma unroll
        for (int sub = 0; sub < 8; ++sub) {
            int k = c * 4 + (sub >> 1);
            AFrag afr[2];
#pragma unroll
            for (int t = 0; t < 2; ++t) {
                int elA = wave * 32 + t * 16 + n;
                float w3f = __uint_as_float(((unsigned int)w3s[elA * 66 + k]) << 16);
                float s = w3f * ((sub & 1) ? Asq4[t] : Asq[t]);
                afr[t].u[0] = pk_bf16(s * Ad[t][0], s * Ad[t][1]);
                afr[t].u[1] = pk_bf16(s * Ad[t][2], s * Ad[t][3]);
                afr[t].u[2] = pk_bf16(s * Ad[t][4], s * Ad[t][5]);
                afr[t].u[3] = pk_bf16(s * Ad[t][6], s * Ad[t][7]);
            }
#pragma unroll
            for (int nt = 0; nt < 2; ++nt) {
                short8 bfrag = *reinterpret_cast<const short8*>(
                    &Bs[buf * 1024 + (sub * 2 + nt) * 64 + lane]);
#pragma unroll
                for (int t = 0; t < 2; ++t) {
                    acc[t][nt] = __builtin_amdgcn_mfma_f32_16x16x32_bf16(
                        afr[t].s8, bfrag, acc[t][nt], 0, 0, 0);
                }
            }
        }
        __syncthreads();
    }

    // epilogue: C/D layout col = lane&15 (wc), row = q*4 + reg (edge)
    const float sc   = 1.0f / 64.0f;
    const float s3c  = 1.7320508075688772f;
    const float s5c  = 2.2360679774997896f;
    const float s15c = 3.872983346207417f;
#pragma unroll
    for (int t = 0; t < 2; ++t) {
#pragma unroll
        for (int r = 0; r < 4; ++r) {
            int e = we0 + t * 16 + q * 4 + r;
            int d = edst[e];
            float* orow = outAcc + d * 60;
            atomicAdd(orow + n, acc[t][0][r] * sc);   // l0, wc = n
            float a1 = acc[t][1][r] * sc;             // wc = 16+n
            if (n < 12) {
                float ux = unit[e * 3], uy = unit[e * 3 + 1], uz = unit[e * 3 + 2];
                if (n < 8) {
                    atomicAdd(orow + 16 + n * 3 + 0, a1 * (s3c * ux));
                    atomicAdd(orow + 16 + n * 3 + 1, a1 * (s3c * uy));
                    atomicAdd(orow + 16 + n * 3 + 2, a1 * (s3c * uz));
                } else {
                    int w = n - 8;
                    atomicAdd(orow + 40 + w * 5 + 0, a1 * (s15c * ux * uz));
                    atomicAdd(orow + 40 + w * 5 + 1, a1 * (s15c * ux * uy));
                    atomicAdd(orow + 40 + w * 5 + 2, a1 * (s5c * (uy * uy - 0.5f * (ux * ux + uz * uz))));
                    atomicAdd(orow + 40 + w * 5 + 3, a1 * (s15c * uy * uz));
                    atomicAdd(orow + 40 + w * 5 + 4, a1 * (0.5f * s15c * (uz * uz - ux * ux)));
                }
            }
            if (n == 0) atomicAdd(counts + d, 1.0f);
        }
    }
}

// ---------------------------------------------------------------------------
// Kernel 5: divide by max(counts, 1)
// ---------------------------------------------------------------------------
__global__ __launch_bounds__(256)
void finalize_kernel(float* __restrict__ out, const float* __restrict__ counts)
{
    int i = blockIdx.x * 256 + threadIdx.x;
    if (i >= NN * 60) return;
    int nd = i / 60;
    out[i] = out[i] / fmaxf(counts[nd], 1.0f);
}

extern "C" void kernel_launch(void* const* d_in, const int* in_sizes, int n_in,
                              void* d_out, int out_size, void* d_ws, size_t ws_size,
                              hipStream_t stream)
{
    const float* pos     = (const float*)d_in[0];
    const int*   A       = (const int*)d_in[1];
    const int*   batch   = (const int*)d_in[2];
    const int*   esrc    = (const int*)d_in[3];
    const int*   edst    = (const int*)d_in[4];
    const float* shifts  = (const float*)d_in[5];
    const float* cell    = (const float*)d_in[6];
    const float* emb_tab = (const float*)d_in[7];
    const float* fitW1   = (const float*)d_in[8];
    const float* fitb1   = (const float*)d_in[9];
    const float* fitW2   = (const float*)d_in[10];
    const float* fitb2   = (const float*)d_in[11];
    const float* fitW3   = (const float*)d_in[12];
    const float* fitb3   = (const float*)d_in[13];
    const float* fcW1    = (const float*)d_in[14];
    const float* fcW2    = (const float*)d_in[15];
    const float* fcW3    = (const float*)d_in[16];
    const float* fcW4    = (const float*)d_in[17];

    float* out = (float*)d_out;

    // workspace layout (floats)
    float* ws      = (float*)d_ws;
    float* Ai      = ws;                              // 80000
    float* counts  = ws + 80000;                      // 10000
    float* unit    = ws + 90000;                      // NE*3 = 393216
    unsigned short* w3gT = (unsigned short*)(ws + 483216);   // NE*64 bf16 = 4194304 floats
    unsigned short* BgU  = (unsigned short*)(ws + 483216 + 4194304); // 131072 bf16 (16B-aligned)
    const uint4* Bg = (const uint4*)BgU;

    hipMemsetAsync(d_out, 0, (size_t)NN * 60 * sizeof(float), stream);
    hipMemsetAsync(counts, 0, (size_t)NN * sizeof(float), stream);

    node_mlp_kernel<<<(NN + 255) / 256, 256, 0, stream>>>(
        A, emb_tab, fitW1, fitb1, fitW2, fitb2, fitW3, fitb3, Ai);

    edge_mlp_kernel<<<NE / 256, 256, 0, stream>>>(
        pos, batch, esrc, edst, shifts, cell, fcW1, fcW2, fcW3, w3gT, unit);

    prep_B_kernel<<<131072 / 256, 256, 0, stream>>>(fcW4, (unsigned short*)BgU);

    gemm_kernel<<<NE / 128, 256, 0, stream>>>(
        esrc, edst, Ai, w3gT, unit, Bg, out, counts);

    finalize_kernel<<<(NN * 60 + 255) / 256, 256, 0, stream>>>(out, counts);
}

// Round 3
// 382.782 us; speedup vs baseline: 2.9207x; 2.4071x over previous
//
#include <hip/hip_runtime.h>
#include <hip/hip_bf16.h>
#include <math.h>

#define NN 10000
#define NE 131072

typedef __attribute__((ext_vector_type(8))) short short8;
typedef __attribute__((ext_vector_type(4))) float f32x4;

__device__ __forceinline__ float silu_f(float x) {
    return x / (1.0f + __expf(-x));
}

// round-to-nearest-even f32 -> bf16 (finite inputs only)
__device__ __forceinline__ unsigned short f2bf(float f) {
    unsigned int u = __float_as_uint(f);
    u += 0x7FFFu + ((u >> 16) & 1u);
    return (unsigned short)(u >> 16);
}

// packed pair via HW v_cvt_pk_bf16_f32 (x = low half)
__device__ __forceinline__ unsigned int pk_bf16(float lo, float hi) {
    __hip_bfloat162 h = __float22bfloat162_rn(float2{lo, hi});
    return *reinterpret_cast<unsigned int*>(&h);
}

// ---------------------------------------------------------------------------
// Kernel 1: per-node MLP  embed(16) -> 64 -> 32 -> 8  (Ai)
// ---------------------------------------------------------------------------
__global__ __launch_bounds__(256)
void node_mlp_kernel(const int* __restrict__ A,
                     const float* __restrict__ emb_tab,
                     const float* __restrict__ W1, const float* __restrict__ b1,
                     const float* __restrict__ W2, const float* __restrict__ b2,
                     const float* __restrict__ W3, const float* __restrict__ b3,
                     float* __restrict__ Ai)
{
    int n = blockIdx.x * blockDim.x + threadIdx.x;
    if (n >= NN) return;
    int a = A[n];
    float h[16];
#pragma unroll
    for (int i = 0; i < 16; ++i) h[i] = emb_tab[a * 16 + i];

    float h1[64];
#pragma unroll
    for (int j = 0; j < 64; ++j) h1[j] = b1[j];
#pragma unroll
    for (int i = 0; i < 16; ++i) {
        float hv = h[i];
#pragma unroll
        for (int j = 0; j < 64; ++j) h1[j] += hv * W1[i * 64 + j];
    }
#pragma unroll
    for (int j = 0; j < 64; ++j) h1[j] = silu_f(h1[j]);

    float h2[32];
#pragma unroll
    for (int j = 0; j < 32; ++j) h2[j] = b2[j];
#pragma unroll
    for (int i = 0; i < 64; ++i) {
        float hv = h1[i];
#pragma unroll
        for (int j = 0; j < 32; ++j) h2[j] += hv * W2[i * 32 + j];
    }
#pragma unroll
    for (int j = 0; j < 32; ++j) h2[j] = silu_f(h2[j]);

#pragma unroll
    for (int j = 0; j < 8; ++j) {
        float s = b3[j];
#pragma unroll
        for (int i = 0; i < 32; ++i) s += h2[i] * W3[i * 8 + j];
        Ai[n * 8 + j] = s;
    }
}

// ---------------------------------------------------------------------------
// Kernel 2: per-edge geometry + radial MLP -> w3 (bf16, transposed [64][NE])
//           + unit vectors [NE*3]
// Block = 64, __launch_bounds__(64): VGPR cap 512 so the ~150-float live set
// (w1v[64]+w2v[64]+temps) stays in registers — round-2's 128-VGPR build
// spilled ~40 floats to scratch and ran 700 us latency-bound.
// TLP is structurally 2 waves/SIMD (131072 threads); ILP must carry it.
// ---------------------------------------------------------------------------
__global__ __launch_bounds__(64)
void edge_mlp_kernel(const float* __restrict__ pos,
                     const int* __restrict__ batch,
                     const int* __restrict__ esrc,
                     const int* __restrict__ edst,
                     const float* __restrict__ shifts,
                     const float* __restrict__ cell,
                     const float* __restrict__ fcW1,
                     const float* __restrict__ fcW2,
                     const float* __restrict__ fcW3,
                     unsigned short* __restrict__ w3gT,
                     float* __restrict__ unit)
{
    int e = blockIdx.x * 64 + threadIdx.x;
    int s = esrc[e], d = edst[e];
    int b = batch[s];
    const float* C = cell + b * 9;
    float sx = shifts[e * 3 + 0], sy = shifts[e * 3 + 1], sz = shifts[e * 3 + 2];
    float vx = pos[d * 3 + 0] - pos[s * 3 + 0] + sx * C[0] + sy * C[3] + sz * C[6];
    float vy = pos[d * 3 + 1] - pos[s * 3 + 1] + sx * C[1] + sy * C[4] + sz * C[7];
    float vz = pos[d * 3 + 2] - pos[s * 3 + 2] + sx * C[2] + sy * C[5] + sz * C[8];
    float len = sqrtf(vx * vx + vy * vy + vz * vz);
    float inv = 1.0f / fmaxf(len, 1e-9f);
    unit[e * 3 + 0] = vx * inv;
    unit[e * 3 + 1] = vy * inv;
    unit[e * 3 + 2] = vz * inv;

    // soft_one_hot: the sqrt(10) of emb and /sqrt(10) of fc_W1 cancel.
    float embv[10];
    float base = len * 2.75f;
#pragma unroll
    for (int i = 0; i < 10; ++i) {
        float dd = base - (float)(i + 1);
        embv[i] = __expf(-dd * dd) * (1.0f / 1.12f);
    }

    // layer 1: w1 = silu(emb @ fcW1)
    float w1v[64];
#pragma unroll
    for (int j = 0; j < 64; ++j) w1v[j] = 0.f;
#pragma unroll
    for (int i = 0; i < 10; ++i) {
        float hv = embv[i];
#pragma unroll
        for (int j = 0; j < 64; ++j) w1v[j] += hv * fcW1[i * 64 + j];
    }
#pragma unroll
    for (int j = 0; j < 64; ++j) w1v[j] = silu_f(w1v[j]);

    // layer 2: w2 = silu(w1 @ fcW2 / 8), computed in chunks of 16 outputs
    // (chunked accumulate + immediate silu keeps peak live set ~144 floats)
    float w2v[64];
#pragma unroll
    for (int jc = 0; jc < 4; ++jc) {
        float accv[16];
#pragma unroll
        for (int j = 0; j < 16; ++j) accv[j] = 0.f;
#pragma unroll
        for (int i = 0; i < 64; ++i) {
            float hv = w1v[i];
#pragma unroll
            for (int j = 0; j < 16; ++j)
                accv[j] += hv * fcW2[i * 64 + jc * 16 + j];
        }
#pragma unroll
        for (int j = 0; j < 16; ++j) w2v[jc * 16 + j] = silu_f(accv[j] * 0.125f);
    }

    // layer 3: w3 = silu(w2 @ fcW3 / 8) -> bf16, transposed global store
#pragma unroll
    for (int jc = 0; jc < 4; ++jc) {
        float accv[16];
#pragma unroll
        for (int j = 0; j < 16; ++j) accv[j] = 0.f;
#pragma unroll
        for (int i = 0; i < 64; ++i) {
            float hv = w2v[i];
#pragma unroll
            for (int j = 0; j < 16; ++j)
                accv[j] += hv * fcW3[i * 64 + jc * 16 + j];
        }
#pragma unroll
        for (int j = 0; j < 16; ++j)
            w3gT[(jc * 16 + j) * NE + e] = f2bf(silu_f(accv[j] * 0.125f));
    }
}

// ---------------------------------------------------------------------------
// Kernel 3: build B = fc_W4 re-laid out as bf16 [K=4096][N=32] pre-swizzled
// into MFMA-fragment order:
//   flat = ((((chunk*8 + sub)*2 + nt)*4 + q)*16 + nn)*8 + j
//   kuv = chunk*256 + sub*32 + q*8 + j ;  wc = nt*16 + nn
// ---------------------------------------------------------------------------
__global__ __launch_bounds__(256)
void prep_B_kernel(const float* __restrict__ fcW4, unsigned short* __restrict__ Bg)
{
    int i = blockIdx.x * 256 + threadIdx.x;   // [0, 131072)
    int j  = i & 7;
    int nn = (i >> 3) & 15;
    int q  = (i >> 7) & 3;
    int nt = (i >> 9) & 1;
    int sub = (i >> 10) & 7;
    int chunk = i >> 13;
    int kuv = (chunk << 8) + (sub << 5) + (q << 3) + j;
    int k = kuv >> 6;
    int uv = kuv & 63;
    int wc = (nt << 4) + nn;
    float v;
    if (wc < 16)      v = fcW4[k * 1792 + uv * 16 + wc];
    else if (wc < 24) v = fcW4[k * 1792 + 1024 + uv * 8 + (wc - 16)];
    else if (wc < 28) v = fcW4[k * 1792 + 1536 + uv * 4 + (wc - 24)];
    else              v = 0.0f;
    Bg[i] = f2bf(v);
}

// ---------------------------------------------------------------------------
// Kernel 4: MFMA GEMM  C[e, wc] = sum_kuv G[e,kuv] * B[kuv,wc]
//   G[e, k*64+u*8+v] = w3[e,k] * As[e,u] * Ad[e,v]   (built in-register)
// ---------------------------------------------------------------------------
__global__ __launch_bounds__(256, 2)
void gemm_kernel(const int* __restrict__ esrc,
                 const int* __restrict__ edst,
                 const float* __restrict__ Ai,
                 const unsigned short* __restrict__ w3gT,
                 const float* __restrict__ unit,
                 const uint4* __restrict__ Bg,
                 float* __restrict__ outAcc,
                 float* __restrict__ counts)
{
    __shared__ uint4 Bs[2048];                 // 2 x 16KB
    __shared__ unsigned short w3s[128 * 66];   // [block-edge][k], +2 pad

    const int tid  = threadIdx.x;
    const int wave = tid >> 6;
    const int lane = tid & 63;
    const int q    = lane >> 4;
    const int n    = lane & 15;
    const int be0  = blockIdx.x * 128;
    const int we0  = be0 + wave * 32;

    // stage w3 for the block's 128 edges: coalesced global, scattered LDS
    {
        const unsigned int* g = (const unsigned int*)w3gT;  // [64][NE/2] uints
        const int colbase = be0 >> 1;
#pragma unroll
        for (int it = 0; it < 16; ++it) {
            int idx = it * 256 + tid;          // 0..4095
            int k  = idx >> 6;
            int cc = idx & 63;
            unsigned int v = g[k * (NE / 2) + colbase + cc];
            w3s[(2 * cc)     * 66 + k] = (unsigned short)(v & 0xFFFFu);
            w3s[(2 * cc + 1) * 66 + k] = (unsigned short)(v >> 16);
        }
    }

    // per-lane loop-invariant edge factors (A-operand rows: m = lane&15)
    float Asq[2], Asq4[2], Ad[2][8];
#pragma unroll
    for (int t = 0; t < 2; ++t) {
        int eA = we0 + t * 16 + n;
        int s = esrc[eA], d = edst[eA];
        Asq[t]  = Ai[s * 8 + q];
        Asq4[t] = Ai[s * 8 + 4 + q];
        float4 d0 = *(const float4*)&Ai[d * 8];
        float4 d1 = *(const float4*)&Ai[d * 8 + 4];
        Ad[t][0] = d0.x; Ad[t][1] = d0.y; Ad[t][2] = d0.z; Ad[t][3] = d0.w;
        Ad[t][4] = d1.x; Ad[t][5] = d1.y; Ad[t][6] = d1.z; Ad[t][7] = d1.w;
    }

    f32x4 acc[2][2];
#pragma unroll
    for (int t = 0; t < 2; ++t)
#pragma unroll
        for (int nt = 0; nt < 2; ++nt)
            acc[t][nt] = (f32x4){0.f, 0.f, 0.f, 0.f};

    auto stage = [&](int chunk, int buf) {
#pragma unroll
        for (int it = 0; it < 4; ++it) {
            int sect = it * 4 + wave;                       // 0..15
            const uint4* gp = Bg + chunk * 1024 + sect * 64 + lane;
            uint4* lp = &Bs[buf * 1024 + sect * 64];        // wave-uniform base
            __builtin_amdgcn_global_load_lds(
                (const __attribute__((address_space(1))) unsigned int*)gp,
                (__attribute__((address_space(3))) unsigned int*)lp,
                16, 0, 0);
        }
    };

    union AFrag { unsigned int u[4]; short8 s8; };

    stage(0, 0);
    __syncthreads();

#pragma unroll 1
    for (int c = 0; c < 16; ++c) {
        int buf = c & 1;
        if (c < 15) stage(c + 1, buf ^ 1);
#pragma unroll
        for (int sub = 0; sub < 8; ++sub) {
            int k = c * 4 + (sub >> 1);
            AFrag afr[2];
#pragma unroll
            for (int t = 0; t < 2; ++t) {
                int elA = wave * 32 + t * 16 + n;
                float w3f = __uint_as_float(((unsigned int)w3s[elA * 66 + k]) << 16);
                float s = w3f * ((sub & 1) ? Asq4[t] : Asq[t]);
                afr[t].u[0] = pk_bf16(s * Ad[t][0], s * Ad[t][1]);
                afr[t].u[1] = pk_bf16(s * Ad[t][2], s * Ad[t][3]);
                afr[t].u[2] = pk_bf16(s * Ad[t][4], s * Ad[t][5]);
                afr[t].u[3] = pk_bf16(s * Ad[t][6], s * Ad[t][7]);
            }
#pragma unroll
            for (int nt = 0; nt < 2; ++nt) {
                short8 bfrag = *reinterpret_cast<const short8*>(
                    &Bs[buf * 1024 + (sub * 2 + nt) * 64 + lane]);
#pragma unroll
                for (int t = 0; t < 2; ++t) {
                    acc[t][nt] = __builtin_amdgcn_mfma_f32_16x16x32_bf16(
                        afr[t].s8, bfrag, acc[t][nt], 0, 0, 0);
                }
            }
        }
        __syncthreads();
    }

    // epilogue: C/D layout col = lane&15 (wc), row = q*4 + reg (edge)
    const float sc   = 1.0f / 64.0f;
    const float s3c  = 1.7320508075688772f;
    const float s5c  = 2.2360679774997896f;
    const float s15c = 3.872983346207417f;
#pragma unroll
    for (int t = 0; t < 2; ++t) {
#pragma unroll
        for (int r = 0; r < 4; ++r) {
            int e = we0 + t * 16 + q * 4 + r;
            int d = edst[e];
            float* orow = outAcc + d * 60;
            atomicAdd(orow + n, acc[t][0][r] * sc);   // l0, wc = n
            float a1 = acc[t][1][r] * sc;             // wc = 16+n
            if (n < 12) {
                float ux = unit[e * 3], uy = unit[e * 3 + 1], uz = unit[e * 3 + 2];
                if (n < 8) {
                    atomicAdd(orow + 16 + n * 3 + 0, a1 * (s3c * ux));
                    atomicAdd(orow + 16 + n * 3 + 1, a1 * (s3c * uy));
                    atomicAdd(orow + 16 + n * 3 + 2, a1 * (s3c * uz));
                } else {
                    int w = n - 8;
                    atomicAdd(orow + 40 + w * 5 + 0, a1 * (s15c * ux * uz));
                    atomicAdd(orow + 40 + w * 5 + 1, a1 * (s15c * ux * uy));
                    atomicAdd(orow + 40 + w * 5 + 2, a1 * (s5c * (uy * uy - 0.5f * (ux * ux + uz * uz))));
                    atomicAdd(orow + 40 + w * 5 + 3, a1 * (s15c * uy * uz));
                    atomicAdd(orow + 40 + w * 5 + 4, a1 * (0.5f * s15c * (uz * uz - ux * ux)));
                }
            }
            if (n == 0) atomicAdd(counts + d, 1.0f);
        }
    }
}

// ---------------------------------------------------------------------------
// Kernel 5: divide by max(counts, 1)
// ---------------------------------------------------------------------------
__global__ __launch_bounds__(256)
void finalize_kernel(float* __restrict__ out, const float* __restrict__ counts)
{
    int i = blockIdx.x * 256 + threadIdx.x;
    if (i >= NN * 60) return;
    int nd = i / 60;
    out[i] = out[i] / fmaxf(counts[nd], 1.0f);
}

extern "C" void kernel_launch(void* const* d_in, const int* in_sizes, int n_in,
                              void* d_out, int out_size, void* d_ws, size_t ws_size,
                              hipStream_t stream)
{
    const float* pos     = (const float*)d_in[0];
    const int*   A       = (const int*)d_in[1];
    const int*   batch   = (const int*)d_in[2];
    const int*   esrc    = (const int*)d_in[3];
    const int*   edst    = (const int*)d_in[4];
    const float* shifts  = (const float*)d_in[5];
    const float* cell    = (const float*)d_in[6];
    const float* emb_tab = (const float*)d_in[7];
    const float* fitW1   = (const float*)d_in[8];
    const float* fitb1   = (const float*)d_in[9];
    const float* fitW2   = (const float*)d_in[10];
    const float* fitb2   = (const float*)d_in[11];
    const float* fitW3   = (const float*)d_in[12];
    const float* fitb3   = (const float*)d_in[13];
    const float* fcW1    = (const float*)d_in[14];
    const float* fcW2    = (const float*)d_in[15];
    const float* fcW3    = (const float*)d_in[16];
    const float* fcW4    = (const float*)d_in[17];

    float* out = (float*)d_out;

    // workspace layout (floats)
    float* ws      = (float*)d_ws;
    float* Ai      = ws;                              // 80000
    float* counts  = ws + 80000;                      // 10000
    float* unit    = ws + 90000;                      // NE*3 = 393216
    unsigned short* w3gT = (unsigned short*)(ws + 483216);   // NE*64 bf16 = 4194304 floats
    unsigned short* BgU  = (unsigned short*)(ws + 483216 + 4194304); // 131072 bf16 (16B-aligned)
    const uint4* Bg = (const uint4*)BgU;

    hipMemsetAsync(d_out, 0, (size_t)NN * 60 * sizeof(float), stream);
    hipMemsetAsync(counts, 0, (size_t)NN * sizeof(float), stream);

    node_mlp_kernel<<<(NN + 255) / 256, 256, 0, stream>>>(
        A, emb_tab, fitW1, fitb1, fitW2, fitb2, fitW3, fitb3, Ai);

    edge_mlp_kernel<<<NE / 64, 64, 0, stream>>>(
        pos, batch, esrc, edst, shifts, cell, fcW1, fcW2, fcW3, w3gT, unit);

    prep_B_kernel<<<131072 / 256, 256, 0, stream>>>(fcW4, (unsigned short*)BgU);

    gemm_kernel<<<NE / 128, 256, 0, stream>>>(
        esrc, edst, Ai, w3gT, unit, Bg, out, counts);

    finalize_kernel<<<(NN * 60 + 255) / 256, 256, 0, stream>>>(out, counts);
}